// Round 4
// baseline (387.597 us; speedup 1.0000x reference)
//
#include <hip/hip_runtime.h>
#include <hip/hip_bf16.h>

// ---------------------------------------------------------------------------
// SpatialInteraction: per-batch channel self-attention
//   S = X X^T  (c=1024, n=4096), attn = softmax_rows(S), out = attn X
// Pipeline: cvt+transpose -> 256^2 bt-GEMM (S) -> softmax -> 256^2 bt-GEMM.
// GEMM: 256x256 tile, BK=64, 512 thr / 8 waves, T2 chunk-XOR swizzle,
// 4-phase counted-vmcnt pipeline, setprio, frag-register reuse (24 ds_reads
// per wave per K-tile instead of 48), T1 bijective XCD swizzle.
// ---------------------------------------------------------------------------

typedef float  f32x4  __attribute__((ext_vector_type(4)));
typedef __bf16 bf16x8 __attribute__((ext_vector_type(8)));

#define BATCH 16
#define C_DIM 1024
#define N_DIM 4096

#define WAITVM(N) asm volatile("s_waitcnt vmcnt(" #N ")" ::: "memory")

__device__ __forceinline__ void fence_() { asm volatile("" ::: "memory"); }
__device__ __forceinline__ void bar_() { fence_(); __builtin_amdgcn_s_barrier(); fence_(); }

__device__ __forceinline__ unsigned short f2bf(float f) {
  unsigned u = __float_as_uint(f);
  u += 0x7fffu + ((u >> 16) & 1u);        // round-to-nearest-even
  return (unsigned short)(u >> 16);
}

__device__ __forceinline__ void gld_lds16(const void* g, void* l) {
  __builtin_amdgcn_global_load_lds(
      (const __attribute__((address_space(1))) unsigned int*)g,
      (__attribute__((address_space(3))) unsigned int*)l, 16, 0, 0);
}

// ---------------------------------------------------------------------------
// Kernel 0: fp32 -> bf16 copy (xb[c][n]) + transposed copy (xbT[n][c]).
// ---------------------------------------------------------------------------
__global__ __launch_bounds__(256) void cvt_xpose(const float* __restrict__ x,
                                                 unsigned short* __restrict__ xb,
                                                 unsigned short* __restrict__ xbT) {
  __shared__ unsigned short tile[64][68];
  const int b  = blockIdx.z;
  const int c0 = blockIdx.y * 64;
  const int n0 = blockIdx.x * 64;
  const int t  = threadIdx.x;

  const float* xp = x + ((size_t)b * C_DIM + c0) * N_DIM + n0;
  const int tn = (t & 15) * 4;
  const int tc = t >> 4;

#pragma unroll
  for (int i = 0; i < 4; ++i) {
    const int c = i * 16 + tc;
    const float4 v = *(const float4*)(xp + (size_t)c * N_DIM + tn);
    ushort4 u;
    u.x = f2bf(v.x); u.y = f2bf(v.y); u.z = f2bf(v.z); u.w = f2bf(v.w);
    *(ushort4*)&tile[c][tn] = u;
    *(ushort4*)(xb + ((size_t)b * C_DIM + c0 + c) * N_DIM + n0 + tn) = u;
  }
  __syncthreads();

  const int pc = (t & 15) * 4;
  const int pn = t >> 4;
#pragma unroll
  for (int i = 0; i < 4; ++i) {
    const int n = i * 16 + pn;
    ushort4 u;
    u.x = tile[pc + 0][n];
    u.y = tile[pc + 1][n];
    u.z = tile[pc + 2][n];
    u.w = tile[pc + 3][n];
    *(ushort4*)(xbT + ((size_t)b * N_DIM + n0 + n) * C_DIM + c0 + pc) = u;
  }
}

// ---------------------------------------------------------------------------
// 256^2 bt-GEMM helpers. LDS layout per matrix per buffer: 256 rows x 64
// bf16 (8 x 16B chunks/row); swizzle chunk' = chunk ^ (row & 7), applied to
// the GLOBAL source on stage and to the ds_read address (LDS stays linear).
// ---------------------------------------------------------------------------

// Stage half H (128 rows): 2 x global_load_lds(16B) per thread.
template<int H>
__device__ __forceinline__ void stage_half(const unsigned short* __restrict__ Gb,
                                           int ld, int k0,
                                           unsigned short* matbase, int tid) {
  unsigned short* lhalf = matbase + H * 128 * 64;
#pragma unroll
  for (int i = 0; i < 2; ++i) {
    const int chunk = i * 512 + tid;     // 0..1023 within half
    const int row   = chunk >> 3;        // 0..127
    const int c16   = chunk & 7;
    const int grow  = H * 128 + row;
    gld_lds16(Gb + (size_t)grow * ld + k0 + ((c16 ^ (row & 7)) * 8),
              lhalf + chunk * 8);
  }
}

template<int MH>
__device__ __forceinline__ void loadA(const unsigned short* __restrict__ As,
                                      bf16x8 (&a)[4][2], int wrow, int r, int kg) {
#pragma unroll
  for (int i = 0; i < 4; ++i) {
    const int row = MH * 128 + wrow * 64 + i * 16 + r;
#pragma unroll
    for (int kk = 0; kk < 2; ++kk) {
      const int c = kk * 4 + kg;
      a[i][kk] = *(const bf16x8*)(As + row * 64 + ((c ^ (row & 7)) * 8));
    }
  }
}

template<int NH>
__device__ __forceinline__ void loadB(const unsigned short* __restrict__ Bs,
                                      bf16x8 (&b)[2][2], int wcol, int r, int kg) {
#pragma unroll
  for (int j = 0; j < 2; ++j) {
    const int row = NH * 128 + wcol * 32 + j * 16 + r;
#pragma unroll
    for (int kk = 0; kk < 2; ++kk) {
      const int c = kk * 4 + kg;
      b[j][kk] = *(const bf16x8*)(Bs + row * 64 + ((c ^ (row & 7)) * 8));
    }
  }
}

// 16 MFMA: A-half MH x B-half NH over K=64, frags already in registers.
template<int MH, int NH>
__device__ __forceinline__ void mfma16(const bf16x8 (&a)[4][2],
                                       const bf16x8 (&b)[2][2],
                                       f32x4 (&acc)[8][4]) {
  __builtin_amdgcn_s_setprio(1);
#pragma unroll
  for (int i = 0; i < 4; ++i)
#pragma unroll
    for (int j = 0; j < 2; ++j)
#pragma unroll
      for (int kk = 0; kk < 2; ++kk)
        acc[MH * 4 + i][NH * 2 + j] = __builtin_amdgcn_mfma_f32_16x16x32_bf16(
            a[i][kk], b[j][kk], acc[MH * 4 + i][NH * 2 + j], 0, 0, 0);
  __builtin_amdgcn_s_setprio(0);
}

// C[M][N] = A[M][K] * B[N][K]^T ; A,B bf16 row-major; C fp32.
// 1D grid = gx * 4 * BATCH blocks, 512 threads. M fixed at 1024 (4 tiles).
__global__ __launch_bounds__(512, 2)
void gemm_bt256(const unsigned short* __restrict__ A,
                const unsigned short* __restrict__ B,
                float* __restrict__ C,
                int K, int lda, int ldb, int ldc,
                long sA, long sB, long sC, int gx) {
  __shared__ unsigned short lds[2][2][256 * 64];   // [buf][A=0/B=1] : 128 KiB

  // T1: bijective XCD swizzle (nwg % 8 == 0), then y-fastest decode so
  // concurrent blocks on one XCD share B-panels.
  const int nwg  = gridDim.x;
  const int orig = blockIdx.x;
  const int wg   = (orig & 7) * (nwg >> 3) + (orig >> 3);
  const int by   = wg & 3;
  const int bx   = (wg >> 2) % gx;
  const int bz   = wg / (gx * 4);

  const int tid  = threadIdx.x;
  const int lane = tid & 63;
  const int wid  = tid >> 6;
  const int wrow = wid >> 2;      // 0..1
  const int wcol = wid & 3;       // 0..3
  const int r    = lane & 15;
  const int kg   = lane >> 4;     // 0..3

  const unsigned short* Ab = A + (size_t)bz * sA + (size_t)by * 256 * lda;
  const unsigned short* Bb = B + (size_t)bz * sB + (size_t)bx * 256 * ldb;

  f32x4 acc[8][4] = {};
  bf16x8 a[4][2], b0[2][2], b1[2][2];
  const int NT = K / 64;

  // ---- prologue: stage tile 0 into buf0, queue order A0,B0,B1,A1 ----
  stage_half<0>(Ab, lda, 0, &lds[0][0][0], tid);
  stage_half<0>(Bb, ldb, 0, &lds[0][1][0], tid);
  stage_half<1>(Bb, ldb, 0, &lds[0][1][0], tid);
  stage_half<1>(Ab, lda, 0, &lds[0][0][0], tid);

  // ---- main loop: tiles 0..NT-2, prefetching t+1 ----
  // Steady-state queue at ph1 entry (oldest->newest): A0,B0,B1,A1 (2 each).
  for (int t = 0; t < NT - 1; ++t) {
    const unsigned short* Ac = &lds[t & 1][0][0];
    const unsigned short* Bc = &lds[t & 1][1][0];
    unsigned short* An = &lds[(t + 1) & 1][0][0];
    unsigned short* Bn = &lds[(t + 1) & 1][1][0];
    const int k1 = (t + 1) * 64;

    // ph1: needs A0,B0 -> drain to 2 (leave B1,A1)
    WAITVM(2); bar_();
    stage_half<0>(Ab, lda, k1, An, tid);   // A0' of t+1
    stage_half<0>(Bb, ldb, k1, Bn, tid);   // B0' of t+1
    loadA<0>(Ac, a, wrow, r, kg);
    loadB<0>(Bc, b0, wcol, r, kg);
    mfma16<0, 0>(a, b0, acc);

    // ph2: needs B1 -> queue [B1,A1,A0',B0'] -> drain to 3
    WAITVM(3); bar_();
    stage_half<1>(Bb, ldb, k1, Bn, tid);   // B1' of t+1
    loadB<1>(Bc, b1, wcol, r, kg);
    mfma16<0, 1>(a, b1, acc);

    // ph3: needs A1 -> queue [A1,A0',B0',B1'] -> drain to 3
    WAITVM(3); bar_();
    stage_half<1>(Ab, lda, k1, An, tid);   // A1' of t+1
    loadA<1>(Ac, a, wrow, r, kg);          // overwrite A regs
    mfma16<1, 0>(a, b0, acc);
    mfma16<1, 1>(a, b1, acc);              // ph4: register-only
  }

  // ---- peeled last tile: drain 2 -> 1 -> 0 ----
  {
    const unsigned short* Ac = &lds[(NT - 1) & 1][0][0];
    const unsigned short* Bc = &lds[(NT - 1) & 1][1][0];
    WAITVM(2); bar_();
    loadA<0>(Ac, a, wrow, r, kg);
    loadB<0>(Bc, b0, wcol, r, kg);
    mfma16<0, 0>(a, b0, acc);
    WAITVM(1); bar_();
    loadB<1>(Bc, b1, wcol, r, kg);
    mfma16<0, 1>(a, b1, acc);
    WAITVM(0); bar_();
    loadA<1>(Ac, a, wrow, r, kg);
    mfma16<1, 0>(a, b0, acc);
    mfma16<1, 1>(a, b1, acc);
  }

  // ---- epilogue: C/D layout col = lane&15, row = (lane>>4)*4 + j ----
  float* Cb = C + (size_t)bz * sC;
  const int rb = by * 256;
  const int cb = bx * 256;
#pragma unroll
  for (int m = 0; m < 8; ++m) {
    const int row = rb + (m >> 2) * 128 + wrow * 64 + (m & 3) * 16 + kg * 4;
#pragma unroll
    for (int n = 0; n < 4; ++n) {
      const int col = cb + (n >> 1) * 128 + wcol * 32 + (n & 1) * 16 + r;
      const f32x4 v = acc[m][n];
#pragma unroll
      for (int j = 0; j < 4; ++j)
        Cb[(size_t)(row + j) * ldc + col] = v[j];
    }
  }
}

// ---------------------------------------------------------------------------
// Kernel 2: row softmax, S (fp32, 16384 rows x 1024) -> attn (bf16).
// ---------------------------------------------------------------------------
__global__ __launch_bounds__(256) void softmax_rows(const float* __restrict__ S,
                                                    unsigned short* __restrict__ P) {
  __shared__ float redm[4];
  __shared__ float reds[4];
  const int t = threadIdx.x;
  const int wid = t >> 6, lane = t & 63;
  const size_t row = blockIdx.x;

  const float4 v = ((const float4*)(S + row * 1024))[t];

  float m = fmaxf(fmaxf(v.x, v.y), fmaxf(v.z, v.w));
#pragma unroll
  for (int o = 32; o >= 1; o >>= 1) m = fmaxf(m, __shfl_xor(m, o));
  if (lane == 0) redm[wid] = m;
  __syncthreads();
  m = fmaxf(fmaxf(redm[0], redm[1]), fmaxf(redm[2], redm[3]));

  const float e0 = expf(v.x - m), e1 = expf(v.y - m);
  const float e2 = expf(v.z - m), e3 = expf(v.w - m);
  float s = (e0 + e1) + (e2 + e3);
#pragma unroll
  for (int o = 32; o >= 1; o >>= 1) s += __shfl_xor(s, o);
  if (lane == 0) reds[wid] = s;
  __syncthreads();
  s = (reds[0] + reds[1]) + (reds[2] + reds[3]);

  const float inv = 1.0f / s;
  ushort4 u;
  u.x = f2bf(e0 * inv); u.y = f2bf(e1 * inv);
  u.z = f2bf(e2 * inv); u.w = f2bf(e3 * inv);
  ((ushort4*)(P + row * 1024))[t] = u;
}

// ---------------------------------------------------------------------------
extern "C" void kernel_launch(void* const* d_in, const int* in_sizes, int n_in,
                              void* d_out, int out_size, void* d_ws, size_t ws_size,
                              hipStream_t stream) {
  const float* x = (const float*)d_in[0];
  float* out = (float*)d_out;

  unsigned short* xb   = (unsigned short*)d_ws;
  unsigned short* xbT  = xb + (size_t)BATCH * C_DIM * N_DIM;
  unsigned short* attn = xb;          // overlays xb (dead after GEMM1)
  float* S = out;                     // scores staged in d_out, overwritten later

  cvt_xpose<<<dim3(N_DIM / 64, C_DIM / 64, BATCH), 256, 0, stream>>>(x, xb, xbT);

  // S[c][d] = sum_n xb[c][n] xb[d][n]   (M=N=1024, K=4096) : gx = 4
  gemm_bt256<<<dim3((C_DIM / 256) * (C_DIM / 256) * BATCH), 512, 0, stream>>>(
      xb, xb, S, N_DIM, N_DIM, N_DIM, C_DIM,
      (long)C_DIM * N_DIM, (long)C_DIM * N_DIM, (long)C_DIM * C_DIM,
      C_DIM / 256);

  softmax_rows<<<dim3(BATCH * C_DIM), 256, 0, stream>>>(S, attn);

  // out[c][n] = sum_d attn[c][d] xbT[n][d]  (M=1024, N=4096, K=1024) : gx = 16
  gemm_bt256<<<dim3((N_DIM / 256) * (C_DIM / 256) * BATCH), 512, 0, stream>>>(
      attn, xbT, out, C_DIM, C_DIM, C_DIM, N_DIM,
      (long)C_DIM * C_DIM, (long)N_DIM * C_DIM, (long)C_DIM * N_DIM,
      N_DIM / 256);
}

// Round 5
// 380.021 us; speedup vs baseline: 1.0199x; 1.0199x over previous
//
#include <hip/hip_runtime.h>
#include <hip/hip_bf16.h>

// ---------------------------------------------------------------------------
// SpatialInteraction: per-batch channel self-attention
//   S = X X^T  (c=1024, n=4096), attn = softmax_rows(S), out = attn X
// Pipeline: cvt+transpose -> 256^2 bt-GEMM (S) -> softmax -> 256^2 bt-GEMM.
// R5 GEMM: 256x256 tile, BK=64, 8 waves, T2 chunk-XOR swizzle, checkpoint
// pipeline (2 counted-vmcnt waits + 2 barriers per K-tile, never vmcnt 0),
// setprio MFMA clusters, LDS-transpose vectorized epilogue, T1 XCD swizzle.
// ---------------------------------------------------------------------------

typedef float  f32x4  __attribute__((ext_vector_type(4)));
typedef __bf16 bf16x8 __attribute__((ext_vector_type(8)));

#define BATCH 16
#define C_DIM 1024
#define N_DIM 4096

#define WAITVM(N) asm volatile("s_waitcnt vmcnt(" #N ")" ::: "memory")

__device__ __forceinline__ void bar_() {
  asm volatile("" ::: "memory");
  __builtin_amdgcn_s_barrier();
  asm volatile("" ::: "memory");
}

__device__ __forceinline__ unsigned short f2bf(float f) {
  unsigned u = __float_as_uint(f);
  u += 0x7fffu + ((u >> 16) & 1u);        // round-to-nearest-even
  return (unsigned short)(u >> 16);
}

__device__ __forceinline__ void gld_lds16(const void* g, void* l) {
  __builtin_amdgcn_global_load_lds(
      (const __attribute__((address_space(1))) unsigned int*)g,
      (__attribute__((address_space(3))) unsigned int*)l, 16, 0, 0);
}

// ---------------------------------------------------------------------------
// Kernel 0: fp32 -> bf16 copy (xb[c][n]) + transposed copy (xbT[n][c]).
// ---------------------------------------------------------------------------
__global__ __launch_bounds__(256) void cvt_xpose(const float* __restrict__ x,
                                                 unsigned short* __restrict__ xb,
                                                 unsigned short* __restrict__ xbT) {
  __shared__ unsigned short tile[64][68];
  const int b  = blockIdx.z;
  const int c0 = blockIdx.y * 64;
  const int n0 = blockIdx.x * 64;
  const int t  = threadIdx.x;

  const float* xp = x + ((size_t)b * C_DIM + c0) * N_DIM + n0;
  const int tn = (t & 15) * 4;
  const int tc = t >> 4;

#pragma unroll
  for (int i = 0; i < 4; ++i) {
    const int c = i * 16 + tc;
    const float4 v = *(const float4*)(xp + (size_t)c * N_DIM + tn);
    ushort4 u;
    u.x = f2bf(v.x); u.y = f2bf(v.y); u.z = f2bf(v.z); u.w = f2bf(v.w);
    *(ushort4*)&tile[c][tn] = u;
    *(ushort4*)(xb + ((size_t)b * C_DIM + c0 + c) * N_DIM + n0 + tn) = u;
  }
  __syncthreads();

  const int pc = (t & 15) * 4;
  const int pn = t >> 4;
#pragma unroll
  for (int i = 0; i < 4; ++i) {
    const int n = i * 16 + pn;
    ushort4 u;
    u.x = tile[pc + 0][n];
    u.y = tile[pc + 1][n];
    u.z = tile[pc + 2][n];
    u.w = tile[pc + 3][n];
    *(ushort4*)(xbT + ((size_t)b * N_DIM + n0 + n) * C_DIM + c0 + pc) = u;
  }
}

// ---------------------------------------------------------------------------
// 256^2 bt-GEMM helpers. LDS layout per matrix per buffer: 256 rows x 64
// bf16 (8 x 16B chunks/row); swizzle chunk' = chunk ^ (row & 7), applied to
// the GLOBAL source on stage and to the ds_read address (LDS stays linear).
// ---------------------------------------------------------------------------

template<int H>
__device__ __forceinline__ void stage_half(const unsigned short* __restrict__ Gb,
                                           int ld, int k0,
                                           unsigned short* matbase, int tid) {
  unsigned short* lhalf = matbase + H * 128 * 64;
#pragma unroll
  for (int i = 0; i < 2; ++i) {
    const int chunk = i * 512 + tid;     // 0..1023 within half
    const int row   = chunk >> 3;        // 0..127
    const int c16   = chunk & 7;
    const int grow  = H * 128 + row;
    gld_lds16(Gb + (size_t)grow * ld + k0 + ((c16 ^ (row & 7)) * 8),
              lhalf + chunk * 8);
  }
}

template<int MH>
__device__ __forceinline__ void loadA(const unsigned short* __restrict__ As,
                                      bf16x8 (&a)[4][2], int wrow, int r, int kg) {
#pragma unroll
  for (int i = 0; i < 4; ++i) {
    const int row = MH * 128 + wrow * 64 + i * 16 + r;
#pragma unroll
    for (int kk = 0; kk < 2; ++kk) {
      const int c = kk * 4 + kg;
      a[i][kk] = *(const bf16x8*)(As + row * 64 + ((c ^ (row & 7)) * 8));
    }
  }
}

template<int NH>
__device__ __forceinline__ void loadB(const unsigned short* __restrict__ Bs,
                                      bf16x8 (&b)[2][2], int wcol, int r, int kg) {
#pragma unroll
  for (int j = 0; j < 2; ++j) {
    const int row = NH * 128 + wcol * 32 + j * 16 + r;
#pragma unroll
    for (int kk = 0; kk < 2; ++kk) {
      const int c = kk * 4 + kg;
      b[j][kk] = *(const bf16x8*)(Bs + row * 64 + ((c ^ (row & 7)) * 8));
    }
  }
}

template<int MH, int NH>
__device__ __forceinline__ void mfma16(const bf16x8 (&a)[4][2],
                                       const bf16x8 (&b)[2][2],
                                       f32x4 (&acc)[8][4]) {
  __builtin_amdgcn_s_setprio(1);
#pragma unroll
  for (int i = 0; i < 4; ++i)
#pragma unroll
    for (int j = 0; j < 2; ++j)
#pragma unroll
      for (int kk = 0; kk < 2; ++kk)
        acc[MH * 4 + i][NH * 2 + j] = __builtin_amdgcn_mfma_f32_16x16x32_bf16(
            a[i][kk], b[j][kk], acc[MH * 4 + i][NH * 2 + j], 0, 0, 0);
  __builtin_amdgcn_s_setprio(0);
}

// C[M][N] = A[M][K] * B[N][K]^T ; A,B bf16 row-major; C fp32.
// 1D grid = gx * 4 * BATCH blocks, 512 threads. M fixed at 1024 (4 tiles).
__global__ __launch_bounds__(512, 2)
void gemm_bt256(const unsigned short* __restrict__ A,
                const unsigned short* __restrict__ B,
                float* __restrict__ C,
                int K, int lda, int ldb, int ldc,
                long sA, long sB, long sC, int gx) {
  __shared__ __align__(16) unsigned char smem[131072];  // 2 bufs x (A+B tiles)
  unsigned short* lds = (unsigned short*)smem;
  // buf t: A at (t&1)*32768, B at (t&1)*32768 + 16384 (in shorts)

  // T1: bijective XCD swizzle (nwg % 8 == 0), y-fastest decode.
  const int nwg  = gridDim.x;
  const int orig = blockIdx.x;
  const int wg   = (orig & 7) * (nwg >> 3) + (orig >> 3);
  const int by   = wg & 3;
  const int bx   = (wg >> 2) % gx;
  const int bz   = wg / (gx * 4);

  const int tid  = threadIdx.x;
  const int lane = tid & 63;
  const int wid  = tid >> 6;
  const int wrow = wid >> 2;      // 0..1
  const int wcol = wid & 3;       // 0..3
  const int r    = lane & 15;
  const int kg   = lane >> 4;     // 0..3

  const unsigned short* Ab = A + (size_t)bz * sA + (size_t)by * 256 * lda;
  const unsigned short* Bb = B + (size_t)bz * sB + (size_t)bx * 256 * ldb;

  f32x4 acc[8][4] = {};
  bf16x8 a[4][2], b0[2][2], b1[2][2];
  const int NT = K / 64;

  // ---- prologue: stage tile 0 in checkpoint-group order A0,B0,B1,A1 ----
  {
    unsigned short* A0 = lds;          // buf 0
    unsigned short* B0 = lds + 16384;
    stage_half<0>(Ab, lda, 0, A0, tid);
    stage_half<0>(Bb, ldb, 0, B0, tid);
    stage_half<1>(Bb, ldb, 0, B0, tid);
    stage_half<1>(Ab, lda, 0, A0, tid);
  }
  WAITVM(2); bar_();   // A0,B0,B1 of tile 0 landed (A1 still in flight)

  // ---- main loop: tiles 0..NT-2, staging tile t+1 ----
  // steady-state in-flight queue (oldest->newest), 2 instr per group:
  //   at seg1 entry: [A1(t), A0'(t+1)... ] builds to 8 by CP_mid.
  for (int t = 0; t < NT - 1; ++t) {
    const unsigned short* Ac = lds + (t & 1) * 32768;
    const unsigned short* Bc = Ac + 16384;
    unsigned short* An = lds + ((t + 1) & 1) * 32768;
    unsigned short* Bn = An + 16384;
    const int k1 = (t + 1) * 64;

    // ---- seg1: stage {A0',B0',B1'}; compute quads (0,0),(0,1) ----
    stage_half<0>(Ab, lda, k1, An, tid);
    stage_half<0>(Bb, ldb, k1, Bn, tid);
    stage_half<1>(Bb, ldb, k1, Bn, tid);
    loadA<0>(Ac, a, wrow, r, kg);
    loadB<0>(Bc, b0, wcol, r, kg);
    mfma16<0, 0>(a, b0, acc);
    loadB<1>(Bc, b1, wcol, r, kg);
    mfma16<0, 1>(a, b1, acc);
    // CP_mid: queue [A1(t), A0',B0',B1'] = 8 -> drain A1(t)
    WAITVM(6); bar_();

    // ---- seg2: stage {A1'}; compute quads (1,0),(1,1) ----
    stage_half<1>(Ab, lda, k1, An, tid);
    loadA<1>(Ac, a, wrow, r, kg);
    mfma16<1, 0>(a, b0, acc);
    mfma16<1, 1>(a, b1, acc);
    // CP_end: queue [A0',B0',B1', A1'] = 8 -> drain A0',B0',B1'
    WAITVM(2); bar_();
  }

  // ---- peeled last tile ----
  {
    const unsigned short* Ac = lds + ((NT - 1) & 1) * 32768;
    const unsigned short* Bc = Ac + 16384;
    loadA<0>(Ac, a, wrow, r, kg);
    loadB<0>(Bc, b0, wcol, r, kg);
    mfma16<0, 0>(a, b0, acc);
    loadB<1>(Bc, b1, wcol, r, kg);
    mfma16<0, 1>(a, b1, acc);
    WAITVM(0); bar_();               // A1 of last tile landed
    loadA<1>(Ac, a, wrow, r, kg);
    mfma16<1, 0>(a, b0, acc);
    mfma16<1, 1>(a, b1, acc);
  }

  // ---- epilogue: LDS transpose -> coalesced dwordx4 stores ----
  // acc layout: row = (m>>2)*128 + wrow*64 + (m&3)*16 + kg*4 + j, col =
  // (n>>1)*128 + wcol*32 + (n&1)*16 + r. Process 4 quarters of 64 rows.
  float* Cb = C + (size_t)bz * sC;
  const int rb = by * 256;
  const int cb = bx * 256;
  float* lf = (float*)smem;          // 64 x 260 f32 = 66.6 KiB scratch
  __syncthreads();                   // all LDS reads done before overwrite
#pragma unroll
  for (int q = 0; q < 4; ++q) {
    if (wrow == (q & 1)) {
      const int MH = q >> 1;
#pragma unroll
      for (int i = 0; i < 4; ++i) {
#pragma unroll
        for (int n = 0; n < 4; ++n) {
          const int col  = (n >> 1) * 128 + wcol * 32 + (n & 1) * 16 + r;
          const int lrow = i * 16 + kg * 4;
          const f32x4 v = acc[MH * 4 + i][n];
#pragma unroll
          for (int j = 0; j < 4; ++j)
            lf[(lrow + j) * 260 + col] = v[j];
        }
      }
    }
    __syncthreads();
#pragma unroll
    for (int i = 0; i < 8; ++i) {
      const int chunk = i * 512 + tid;     // 0..4095
      const int row   = chunk >> 6;        // 0..63
      const int cp    = (chunk & 63) * 4;  // 0..252
      const f32x4 v = *(const f32x4*)&lf[row * 260 + cp];
      *(f32x4*)&Cb[(size_t)(rb + q * 64 + row) * ldc + cb + cp] = v;
    }
    __syncthreads();
  }
}

// ---------------------------------------------------------------------------
// Kernel 2: row softmax, S (fp32, 16384 rows x 1024) -> attn (bf16).
// ---------------------------------------------------------------------------
__global__ __launch_bounds__(256) void softmax_rows(const float* __restrict__ S,
                                                    unsigned short* __restrict__ P) {
  __shared__ float redm[4];
  __shared__ float reds[4];
  const int t = threadIdx.x;
  const int wid = t >> 6, lane = t & 63;
  const size_t row = blockIdx.x;

  const float4 v = ((const float4*)(S + row * 1024))[t];

  float m = fmaxf(fmaxf(v.x, v.y), fmaxf(v.z, v.w));
#pragma unroll
  for (int o = 32; o >= 1; o >>= 1) m = fmaxf(m, __shfl_xor(m, o));
  if (lane == 0) redm[wid] = m;
  __syncthreads();
  m = fmaxf(fmaxf(redm[0], redm[1]), fmaxf(redm[2], redm[3]));

  const float e0 = expf(v.x - m), e1 = expf(v.y - m);
  const float e2 = expf(v.z - m), e3 = expf(v.w - m);
  float s = (e0 + e1) + (e2 + e3);
#pragma unroll
  for (int o = 32; o >= 1; o >>= 1) s += __shfl_xor(s, o);
  if (lane == 0) reds[wid] = s;
  __syncthreads();
  s = (reds[0] + reds[1]) + (reds[2] + reds[3]);

  const float inv = 1.0f / s;
  ushort4 u;
  u.x = f2bf(e0 * inv); u.y = f2bf(e1 * inv);
  u.z = f2bf(e2 * inv); u.w = f2bf(e3 * inv);
  ((ushort4*)(P + row * 1024))[t] = u;
}

// ---------------------------------------------------------------------------
extern "C" void kernel_launch(void* const* d_in, const int* in_sizes, int n_in,
                              void* d_out, int out_size, void* d_ws, size_t ws_size,
                              hipStream_t stream) {
  const float* x = (const float*)d_in[0];
  float* out = (float*)d_out;

  unsigned short* xb   = (unsigned short*)d_ws;
  unsigned short* xbT  = xb + (size_t)BATCH * C_DIM * N_DIM;
  unsigned short* attn = xb;          // overlays xb (dead after GEMM1)
  float* S = out;                     // scores staged in d_out, overwritten later

  cvt_xpose<<<dim3(N_DIM / 64, C_DIM / 64, BATCH), 256, 0, stream>>>(x, xb, xbT);

  // S[c][d] = sum_n xb[c][n] xb[d][n]   (M=N=1024, K=4096) : gx = 4
  gemm_bt256<<<dim3((C_DIM / 256) * (C_DIM / 256) * BATCH), 512, 0, stream>>>(
      xb, xb, S, N_DIM, N_DIM, N_DIM, C_DIM,
      (long)C_DIM * N_DIM, (long)C_DIM * N_DIM, (long)C_DIM * C_DIM,
      C_DIM / 256);

  softmax_rows<<<dim3(BATCH * C_DIM), 256, 0, stream>>>(S, attn);

  // out[c][n] = sum_d attn[c][d] xbT[n][d]  (M=1024, N=4096, K=1024) : gx = 16
  gemm_bt256<<<dim3((N_DIM / 256) * (C_DIM / 256) * BATCH), 512, 0, stream>>>(
      attn, xbT, out, C_DIM, C_DIM, C_DIM, N_DIM,
      (long)C_DIM * C_DIM, (long)N_DIM * C_DIM, (long)C_DIM * N_DIM,
      N_DIM / 256);
}